// Round 4
// baseline (282.746 us; speedup 1.0000x reference)
//
#include <hip/hip_runtime.h>
#include <stdint.h>

// UKF with affine motion model == exact Kalman filter (sigma-point machinery
// collapses exactly: Wm sums to 1; Sum_i Wc_i dX_i dX_i^T telescopes to
// F (L L^T) F^T = F P F^T since gamma^2 * 2 * 0.5/(n+lam) = 1).
// Inputs fp32 (proven: R1 bf16-read NaN'd). Outputs fp32 (proven: R2/R3's
// 8.234 error == mechanical signature of bf16-packed writes read as fp32).
// One thread per batch element; t blocked by 4; P held as symmetric triangle.

static constexpr float DTc = 0.1f;

__global__ __launch_bounds__(64) void ukf_kf_kernel(
    const float* __restrict__ meas,   // (B, 2, S)
    const float* __restrict__ stin,   // (B, 4)
    const float* __restrict__ covin,  // (B, 4, 4)
    const float* __restrict__ ctrl,   // (B, S, 2)
    const float* __restrict__ Qp,     // (4,4)
    const float* __restrict__ Rp,     // (2,2)
    float* __restrict__ out,          // fp32: preds (B,2,S) | states (B,4,S) | covs (B,4,4,S)
    int B, int S)
{
    const int b = blockIdx.x * 64 + threadIdx.x;
    if (b >= B) return;

    float4 s4 = *reinterpret_cast<const float4*>(stin + (size_t)b * 4);
    float x0 = s4.x, x1 = s4.y, x2 = s4.z, x3 = s4.w;

    // symmetric P triangle
    float p00, p01, p02, p03, p11, p12, p13, p22, p23, p33;
    {
        const float4* pc = reinterpret_cast<const float4*>(covin + (size_t)b * 16);
        float4 r0 = pc[0], r1 = pc[1], r2 = pc[2], r3 = pc[3];
        p00 = r0.x; p01 = r0.y; p02 = r0.z; p03 = r0.w;
        p11 = r1.y; p12 = r1.z; p13 = r1.w;
        p22 = r2.z; p23 = r2.w;
        p33 = r3.w;
    }
    float q00, q01, q02, q03, q11, q12, q13, q22, q23, q33;
    {
        const float4* pq = reinterpret_cast<const float4*>(Qp);
        float4 r0 = pq[0], r1 = pq[1], r2 = pq[2], r3 = pq[3];
        q00 = r0.x; q01 = r0.y; q02 = r0.z; q03 = r0.w;
        q11 = r1.y; q12 = r1.z; q13 = r1.w;
        q22 = r2.z; q23 = r2.w;
        q33 = r3.w;
    }
    float R00, R01, R10, R11;
    {
        float4 r = *reinterpret_cast<const float4*>(Rp);
        R00 = r.x; R01 = r.y; R10 = r.z; R11 = r.w;
    }

    const float4* pm0 = reinterpret_cast<const float4*>(meas + (size_t)b * 2 * S);
    const float4* pm1 = reinterpret_cast<const float4*>(meas + (size_t)b * 2 * S + S);
    const float4* pu  = reinterpret_cast<const float4*>(ctrl + (size_t)b * S * 2);

    float* preds  = out + (size_t)b * 2 * S;
    float* states = out + (size_t)B * 2 * S + (size_t)b * 4 * S;
    float* covs   = out + (size_t)B * 6 * S + (size_t)b * 16 * S;

    const int NT = S / 4;

    float4 m0 = pm0[0], m1 = pm1[0], u0 = pu[0], u1 = pu[1];

    for (int tb = 0; tb < NT; ++tb) {
        float4 nm0 = make_float4(0, 0, 0, 0), nm1 = nm0, nu0 = nm0, nu1 = nm0;
        if (tb + 1 < NT) {
            nm0 = pm0[tb + 1];
            nm1 = pm1[tb + 1];
            nu0 = pu[2 * tb + 2];
            nu1 = pu[2 * tb + 3];
        }

        const float zb0[4] = { m0.x, m0.y, m0.z, m0.w };
        const float zb1[4] = { m1.x, m1.y, m1.z, m1.w };
        const float uxb[4] = { u0.x, u0.z, u1.x, u1.z };
        const float uyb[4] = { u0.y, u0.w, u1.y, u1.w };

        float pr[2][4];    // preds rows (j, k)
        float st[4][4];    // states rows (j, k)
        float cb[16][4];   // covs rows (i*4+l, k)

#pragma unroll
        for (int k = 0; k < 4; ++k) {
            const float ux = uxb[k], uy = uyb[k];

            // x_pred = F x + B u
            const float xp0 = x0 + DTc * x2 + 0.5f * ux * DTc * DTc;
            const float xp1 = x1 + DTc * x3 + 0.5f * uy * DTc * DTc;
            const float xp2 = x2 + DTc * ux;
            const float xp3 = x3 + DTc * uy;

            // A = F P F^T (exact collapse of Sum Wc dX dX^T; symmetric triangle)
            const float FP00 = p00 + DTc * p02;
            const float FP01 = p01 + DTc * p12;
            const float FP02 = p02 + DTc * p22;
            const float FP03 = p03 + DTc * p23;
            const float FP11 = p11 + DTc * p13;
            const float FP12 = p12 + DTc * p23;
            const float FP13 = p13 + DTc * p33;

            const float a00 = FP00 + DTc * FP02;
            const float a01 = FP01 + DTc * FP03;
            const float a02 = FP02;
            const float a03 = FP03;
            const float a11 = FP11 + DTc * FP13;
            const float a12 = FP12;
            const float a13 = FP13;
            const float a22 = p22;
            const float a23 = p23;
            const float a33 = p33;

            // S = A[0:2,0:2] + R (no Q!) ; Pxz = A[:,0:2]
            const float s00 = a00 + R00, s01 = a01 + R01;
            const float s10 = a01 + R10, s11 = a11 + R11;
            const float rdet = 1.0f / (s00 * s11 - s01 * s10);
            const float i00 =  s11 * rdet, i01 = -s01 * rdet;
            const float i10 = -s10 * rdet, i11 =  s00 * rdet;

            const float K00 = a00 * i00 + a01 * i10;
            const float K01 = a00 * i01 + a01 * i11;
            const float K10 = a01 * i00 + a11 * i10;
            const float K11 = a01 * i01 + a11 * i11;
            const float K20 = a02 * i00 + a12 * i10;
            const float K21 = a02 * i01 + a12 * i11;
            const float K30 = a03 * i00 + a13 * i10;
            const float K31 = a03 * i01 + a13 * i11;

            const float in0 = zb0[k] - xp0;
            const float in1 = zb1[k] - xp1;
            const float xn0 = xp0 + K00 * in0 + K01 * in1;
            const float xn1 = xp1 + K10 * in0 + K11 * in1;
            const float xn2 = xp2 + K20 * in0 + K21 * in1;
            const float xn3 = xp3 + K30 * in0 + K31 * in1;

            // M = K S
            const float M00 = K00 * s00 + K01 * s10;
            const float M01 = K00 * s01 + K01 * s11;
            const float M10 = K10 * s00 + K11 * s10;
            const float M11 = K10 * s01 + K11 * s11;
            const float M20 = K20 * s00 + K21 * s10;
            const float M21 = K20 * s01 + K21 * s11;
            const float M30 = K30 * s00 + K31 * s10;
            const float M31 = K30 * s01 + K31 * s11;

            // P_new = (A + Q) - (K S) K^T  (symmetric by construction)
            p00 = (a00 + q00) - (M00 * K00 + M01 * K01);
            p01 = (a01 + q01) - (M00 * K10 + M01 * K11);
            p02 = (a02 + q02) - (M00 * K20 + M01 * K21);
            p03 = (a03 + q03) - (M00 * K30 + M01 * K31);
            p11 = (a11 + q11) - (M10 * K10 + M11 * K11);
            p12 = (a12 + q12) - (M10 * K20 + M11 * K21);
            p13 = (a13 + q13) - (M10 * K30 + M11 * K31);
            p22 = (a22 + q22) - (M20 * K20 + M21 * K21);
            p23 = (a23 + q23) - (M20 * K30 + M21 * K31);
            p33 = (a33 + q33) - (M30 * K30 + M31 * K31);

            x0 = xn0; x1 = xn1; x2 = xn2; x3 = xn3;

            pr[0][k] = xp0; pr[1][k] = xp1;
            st[0][k] = xn0; st[1][k] = xn1; st[2][k] = xn2; st[3][k] = xn3;

            cb[ 0][k] = p00; cb[ 1][k] = p01; cb[ 2][k] = p02; cb[ 3][k] = p03;
            cb[ 4][k] = p01; cb[ 5][k] = p11; cb[ 6][k] = p12; cb[ 7][k] = p13;
            cb[ 8][k] = p02; cb[ 9][k] = p12; cb[10][k] = p22; cb[11][k] = p23;
            cb[12][k] = p03; cb[13][k] = p13; cb[14][k] = p23; cb[15][k] = p33;
        }

        const int t0 = tb * 4;
        *reinterpret_cast<float4*>(preds + t0)     = *reinterpret_cast<float4*>(pr[0]);
        *reinterpret_cast<float4*>(preds + S + t0) = *reinterpret_cast<float4*>(pr[1]);
#pragma unroll
        for (int j = 0; j < 4; j++)
            *reinterpret_cast<float4*>(states + j * S + t0) = *reinterpret_cast<float4*>(st[j]);
#pragma unroll
        for (int r = 0; r < 16; r++)
            *reinterpret_cast<float4*>(covs + r * S + t0) = *reinterpret_cast<float4*>(cb[r]);

        m0 = nm0; m1 = nm1; u0 = nu0; u1 = nu1;
    }
}

extern "C" void kernel_launch(void* const* d_in, const int* in_sizes, int n_in,
                              void* d_out, int out_size, void* d_ws, size_t ws_size,
                              hipStream_t stream) {
    // Identify inputs by element count (removes order assumptions):
    //   R = 4, Q = 16, cov = 16B, state = 4B, meas == ctrl == 2BS (dict order
    //   among the equal pair: meas before ctrl).
    int iR = -1, iQ = -1, iMeas = -1, iCtrl = -1, iState = -1, iCov = -1;
    for (int i = 0; i < n_in; i++) {
        if (in_sizes[i] == 4 && iR < 0) iR = i;
        else if (in_sizes[i] == 16 && iQ < 0) iQ = i;
    }
    for (int i = 0; i < n_in && iMeas < 0; i++) {
        if (i == iR || i == iQ) continue;
        for (int j = i + 1; j < n_in; j++) {
            if (j == iR || j == iQ) continue;
            if (in_sizes[i] == in_sizes[j]) { iMeas = i; iCtrl = j; break; }
        }
    }
    int rem[2], nrem = 0;
    for (int i = 0; i < n_in && nrem < 2; i++) {
        if (i == iR || i == iQ || i == iMeas || i == iCtrl) continue;
        rem[nrem++] = i;
    }
    if (in_sizes[rem[0]] > in_sizes[rem[1]]) { iCov = rem[0]; iState = rem[1]; }
    else                                     { iCov = rem[1]; iState = rem[0]; }

    const float* meas  = (const float*)d_in[iMeas];
    const float* stin  = (const float*)d_in[iState];
    const float* covin = (const float*)d_in[iCov];
    const float* ctrl  = (const float*)d_in[iCtrl];
    const float* Qp    = (const float*)d_in[iQ];
    const float* Rp    = (const float*)d_in[iR];
    float* out = (float*)d_out;

    const int B = in_sizes[iState] / 4;
    const int S = in_sizes[iMeas] / (2 * B);

    dim3 grid((B + 63) / 64), block(64);
    ukf_kf_kernel<<<grid, block, 0, stream>>>(meas, stin, covin, ctrl, Qp, Rp, out, B, S);
}